// Round 1
// baseline (225.264 us; speedup 1.0000x reference)
//
#include <hip/hip_runtime.h>
#include <math.h>

// NeRF volume-rendering aggregation.
// B=8, R=8192, P=128. One wave (64 lanes) per ray; lane l owns samples l and l+64.
// Memory-bound: ~203 MB traffic -> ~32 us roofline at 6.3 TB/s.

#define FAR_DIST 1e10f
#define EPS_V 1e-10f

constexpr int Bv = 8;
constexpr int Rv = 8192;
constexpr int Pv = 128;
constexpr int NRAYS = Bv * Rv;            // 65536
constexpr int WAVES_PER_BLOCK = 4;        // 256 threads

// Output layout (flat, return order):
// rgb_map   (B,R,3): [0,          196608)
// depth_map (B,R)  : [196608,     262144)
// disp_map  (B,R)  : [262144,     327680)
// alpha_map (B,R)  : [327680,     393216)
// weights (B,R,P)  : [393216,     8781824)
constexpr int OFF_RGB   = 0;
constexpr int OFF_DEPTH = NRAYS * 3;           // 196608
constexpr int OFF_DISP  = OFF_DEPTH + NRAYS;   // 262144
constexpr int OFF_ALPHA = OFF_DISP + NRAYS;    // 327680
constexpr int OFF_W     = OFF_ALPHA + NRAYS;   // 393216

__global__ __launch_bounds__(WAVES_PER_BLOCK * 64)
void nerf_agg_kernel(const float* __restrict__ raw,     // (B,R,P,4)
                     const float* __restrict__ zv,      // (B,R,P)
                     const float* __restrict__ rays_d,  // (B,R,3)
                     const float* __restrict__ bg,      // (3,)
                     float* __restrict__ out)
{
    const int lane = threadIdx.x & 63;
    const int wid  = threadIdx.x >> 6;
    const int ray  = blockIdx.x * WAVES_PER_BLOCK + wid;
    if (ray >= NRAYS) return;

    // ---- coalesced loads: raw samples (float4 = r,g,b,sigma) ----
    const float4* raw4 = (const float4*)(raw + (size_t)ray * (Pv * 4));
    const float4 sA = raw4[lane];        // sample l
    const float4 sB = raw4[lane + 64];   // sample l+64

    const float* zr = zv + (size_t)ray * Pv;
    const float zA = zr[lane];
    const float zB = zr[lane + 64];

    // ---- ray direction norm (same 3 floats for all lanes -> broadcast) ----
    const float* rd = rays_d + (size_t)ray * 3;
    const float dx = rd[0], dy = rd[1], dz = rd[2];
    const float nrm = sqrtf(dx * dx + dy * dy + dz * dz);

    // ---- sample deltas ----
    // zA_next = z[l+1]; for lane 63 that's z[64] = zB of lane 0.
    const float zB0     = __shfl(zB, 0);
    const float zA_roll = __shfl(zA, (lane + 1) & 63);
    const float zB_roll = __shfl(zB, (lane + 1) & 63);
    const float dA = ((lane == 63) ? (zB0 - zA) : (zA_roll - zA)) * nrm;
    const float dB = ((lane == 63) ? FAR_DIST : (zB_roll - zB)) * nrm;

    // ---- alpha ----
    const float sigA = fmaxf(sA.w, 0.0f);
    const float sigB = fmaxf(sB.w, 0.0f);
    const float aA = 1.0f - expf(-sigA * dA);
    const float aB = 1.0f - expf(-sigB * dB);

    // ---- exclusive cumulative transmittance (multiplicative scan) ----
    const float uA = 1.0f - aA + EPS_V;
    const float uB = 1.0f - aB + EPS_V;

    // inclusive scan of uA across lanes
    float s0 = uA;
    #pragma unroll
    for (int off = 1; off < 64; off <<= 1) {
        float t = __shfl_up(s0, off);
        if (lane >= off) s0 *= t;
    }
    const float total0 = __shfl(s0, 63);           // prod of all front-half u
    float eA = __shfl_up(s0, 1);                   // exclusive scan
    const float transA = (lane == 0) ? 1.0f : eA;

    // inclusive scan of uB across lanes
    float s1 = uB;
    #pragma unroll
    for (int off = 1; off < 64; off <<= 1) {
        float t = __shfl_up(s1, off);
        if (lane >= off) s1 *= t;
    }
    float eB = __shfl_up(s1, 1);
    const float transB = total0 * ((lane == 0) ? 1.0f : eB);

    const float wA = aA * transA;
    const float wB = aB * transB;

    // ---- store weights (coalesced) ----
    float* wout = out + OFF_W + (size_t)ray * Pv;
    wout[lane]      = wA;
    wout[lane + 64] = wB;

    // ---- rgb = sigmoid(raw[...,0:3]) ----
    const float rA = 1.0f / (1.0f + expf(-sA.x));
    const float gA = 1.0f / (1.0f + expf(-sA.y));
    const float bA = 1.0f / (1.0f + expf(-sA.z));
    const float rB = 1.0f / (1.0f + expf(-sB.x));
    const float gB = 1.0f / (1.0f + expf(-sB.y));
    const float bB = 1.0f / (1.0f + expf(-sB.z));

    // ---- wave reductions: (w*r, w*g, w*b, w, w*z) ----
    float rr = wA * rA + wB * rB;
    float gg = wA * gA + wB * gB;
    float bb = wA * bA + wB * bB;
    float sw = wA + wB;
    float sz = wA * zA + wB * zB;
    #pragma unroll
    for (int off = 32; off >= 1; off >>= 1) {
        rr += __shfl_xor(rr, off);
        gg += __shfl_xor(gg, off);
        bb += __shfl_xor(bb, off);
        sw += __shfl_xor(sw, off);
        sz += __shfl_xor(sz, off);
    }

    if (lane == 0) {
        // background composite (is_bg = all(bg in [0,1]))
        const float b0 = bg[0], b1 = bg[1], b2 = bg[2];
        const bool is_bg = (b0 >= 0.0f && b0 <= 1.0f) &&
                           (b1 >= 0.0f && b1 <= 1.0f) &&
                           (b2 >= 0.0f && b2 <= 1.0f);
        float orr = rr, ogg = gg, obb = bb;
        if (is_bg) {
            const float rem = 1.0f - sw;
            orr += rem * b0;
            ogg += rem * b1;
            obb += rem * b2;
        }
        out[OFF_RGB + 3 * ray + 0] = orr;
        out[OFF_RGB + 3 * ray + 1] = ogg;
        out[OFF_RGB + 3 * ray + 2] = obb;
        out[OFF_DEPTH + ray] = sz;
        out[OFF_ALPHA + ray] = sw;
        const float disp = 1.0f / (fmaxf(sz / sw - EPS_V, 0.0f) + EPS_V);
        out[OFF_DISP + ray] = disp;
    }
}

extern "C" void kernel_launch(void* const* d_in, const int* in_sizes, int n_in,
                              void* d_out, int out_size, void* d_ws, size_t ws_size,
                              hipStream_t stream) {
    const float* raw    = (const float*)d_in[0];
    const float* zvals  = (const float*)d_in[1];
    const float* rays_d = (const float*)d_in[2];
    const float* bg     = (const float*)d_in[3];
    float* out = (float*)d_out;

    const int blocks = NRAYS / WAVES_PER_BLOCK; // 16384
    nerf_agg_kernel<<<blocks, WAVES_PER_BLOCK * 64, 0, stream>>>(raw, zvals, rays_d, bg, out);
}

// Round 2
// 225.013 us; speedup vs baseline: 1.0011x; 1.0011x over previous
//
#include <hip/hip_runtime.h>
#include <math.h>

// NeRF volume-rendering aggregation — B=8, R=8192, P=128.
// One wave (64 lanes) per ray; lane l owns ADJACENT samples 2l and 2l+1.
// All cross-lane work (cumprod scan + 5 reductions) done with DPP on the
// VALU pipe; only ONE ds_bpermute per wave remains (neighbor-z for deltas).
// Memory-bound target: ~203 MB traffic -> ~34 us at 6 TB/s.

#define FAR_DIST 1e10f
#define EPS_V 1e-10f

constexpr int Bv = 8;
constexpr int Rv = 8192;
constexpr int Pv = 128;
constexpr int NRAYS = Bv * Rv;            // 65536
constexpr int WAVES_PER_BLOCK = 4;        // 256 threads

// Output layout (flat, return order):
constexpr int OFF_RGB   = 0;
constexpr int OFF_DEPTH = NRAYS * 3;           // 196608
constexpr int OFF_DISP  = OFF_DEPTH + NRAYS;   // 262144
constexpr int OFF_ALPHA = OFF_DISP + NRAYS;    // 327680
constexpr int OFF_W     = OFF_ALPHA + NRAYS;   // 393216

// ---- DPP helpers (gfx9/CDNA encodings) ----
// row_shr:N = 0x110+N, row_bcast15 = 0x142, row_bcast31 = 0x143.
// bound_ctrl=false + explicit `old` => invalid/masked lanes yield `old`.
template <int ctrl, int rmask>
__device__ __forceinline__ float dpp_mov(float x, float identity) {
    return __int_as_float(__builtin_amdgcn_update_dpp(
        __float_as_int(identity), __float_as_int(x), ctrl, rmask, 0xf, false));
}

// Inclusive multiplicative scan across the 64-lane wave (6 VALU ops).
__device__ __forceinline__ float wave_incl_prod(float x) {
    x *= dpp_mov<0x111, 0xf>(x, 1.0f);  // row_shr:1
    x *= dpp_mov<0x112, 0xf>(x, 1.0f);  // row_shr:2
    x *= dpp_mov<0x114, 0xf>(x, 1.0f);  // row_shr:4
    x *= dpp_mov<0x118, 0xf>(x, 1.0f);  // row_shr:8
    x *= dpp_mov<0x142, 0xa>(x, 1.0f);  // row_bcast15 -> rows 1,3
    x *= dpp_mov<0x143, 0xc>(x, 1.0f);  // row_bcast31 -> rows 2,3
    return x;
}

// Inclusive additive scan; lane 63 ends with the full wave sum.
__device__ __forceinline__ float wave_sum63(float x) {
    x += dpp_mov<0x111, 0xf>(x, 0.0f);
    x += dpp_mov<0x112, 0xf>(x, 0.0f);
    x += dpp_mov<0x114, 0xf>(x, 0.0f);
    x += dpp_mov<0x118, 0xf>(x, 0.0f);
    x += dpp_mov<0x142, 0xa>(x, 0.0f);
    x += dpp_mov<0x143, 0xc>(x, 0.0f);
    return x;
}

__global__ __launch_bounds__(WAVES_PER_BLOCK * 64)
void nerf_agg_kernel(const float* __restrict__ raw,     // (B,R,P,4)
                     const float* __restrict__ zv,      // (B,R,P)
                     const float* __restrict__ rays_d,  // (B,R,3)
                     const float* __restrict__ bg,      // (3,)
                     float* __restrict__ out)
{
    const int lane = threadIdx.x & 63;
    const int wid  = threadIdx.x >> 6;
    const int ray  = blockIdx.x * WAVES_PER_BLOCK + wid;

    // ---- coalesced loads: two adjacent float4 samples per lane ----
    const float4* raw4 = (const float4*)(raw + (size_t)ray * (Pv * 4));
    const float4 s0 = raw4[2 * lane];
    const float4 s1 = raw4[2 * lane + 1];

    const float2* zr2 = (const float2*)(zv + (size_t)ray * Pv);
    const float2 z01 = zr2[lane];
    const float z0 = z01.x, z1 = z01.y;

    const float* rd = rays_d + (size_t)ray * 3;
    const float dx = rd[0], dy = rd[1], dz = rd[2];
    const float nrm = sqrtf(dx * dx + dy * dy + dz * dz);

    // ---- deltas: d0 in-lane; d1 needs neighbor lane's z0 (one shuffle) ----
    const float z2 = __shfl(z0, (lane + 1) & 63);
    const float d0 = (z1 - z0) * nrm;
    const float d1 = ((lane == 63) ? FAR_DIST : (z2 - z1)) * nrm;

    // ---- alpha & survival u = exp(-relu(sigma)*d) + eps ----
    const float e0 = expf(-fmaxf(s0.w, 0.0f) * d0);
    const float e1 = expf(-fmaxf(s1.w, 0.0f) * d1);
    const float a0 = 1.0f - e0;
    const float a1 = 1.0f - e1;
    const float u0 = e0 + EPS_V;
    const float u1 = e1 + EPS_V;

    // ---- exclusive transmittance via DPP pair-product scan ----
    const float pairU = u0 * u1;
    const float incl  = wave_incl_prod(pairU);
    const float excl  = __fdividef(incl, pairU);   // trans for sample 2l
    const float t0 = excl;
    const float t1 = excl * u0;                    // trans for sample 2l+1

    const float w0 = a0 * t0;
    const float w1 = a1 * t1;

    // ---- store weights (coalesced float2) ----
    float2* wout = (float2*)(out + OFF_W + (size_t)ray * Pv);
    wout[lane] = make_float2(w0, w1);

    // ---- rgb = sigmoid(raw[...,0:3]) ----
    const float r0 = 1.0f / (1.0f + expf(-s0.x));
    const float g0 = 1.0f / (1.0f + expf(-s0.y));
    const float b0v = 1.0f / (1.0f + expf(-s0.z));
    const float r1 = 1.0f / (1.0f + expf(-s1.x));
    const float g1 = 1.0f / (1.0f + expf(-s1.y));
    const float b1v = 1.0f / (1.0f + expf(-s1.z));

    // ---- 5 wave sums via DPP; totals land in lane 63 ----
    const float rr = wave_sum63(w0 * r0 + w1 * r1);
    const float gg = wave_sum63(w0 * g0 + w1 * g1);
    const float bb = wave_sum63(w0 * b0v + w1 * b1v);
    const float sw = wave_sum63(w0 + w1);
    const float sz = wave_sum63(w0 * z0 + w1 * z1);

    if (lane == 63) {
        const float c0 = bg[0], c1 = bg[1], c2 = bg[2];
        const bool is_bg = (c0 >= 0.0f && c0 <= 1.0f) &&
                           (c1 >= 0.0f && c1 <= 1.0f) &&
                           (c2 >= 0.0f && c2 <= 1.0f);
        float orr = rr, ogg = gg, obb = bb;
        if (is_bg) {
            const float rem = 1.0f - sw;
            orr += rem * c0;
            ogg += rem * c1;
            obb += rem * c2;
        }
        out[OFF_RGB + 3 * ray + 0] = orr;
        out[OFF_RGB + 3 * ray + 1] = ogg;
        out[OFF_RGB + 3 * ray + 2] = obb;
        out[OFF_DEPTH + ray] = sz;
        out[OFF_ALPHA + ray] = sw;
        out[OFF_DISP + ray] = 1.0f / (fmaxf(sz / sw - EPS_V, 0.0f) + EPS_V);
    }
}

extern "C" void kernel_launch(void* const* d_in, const int* in_sizes, int n_in,
                              void* d_out, int out_size, void* d_ws, size_t ws_size,
                              hipStream_t stream) {
    const float* raw    = (const float*)d_in[0];
    const float* zvals  = (const float*)d_in[1];
    const float* rays_d = (const float*)d_in[2];
    const float* bg     = (const float*)d_in[3];
    float* out = (float*)d_out;

    const int blocks = NRAYS / WAVES_PER_BLOCK; // 16384
    nerf_agg_kernel<<<blocks, WAVES_PER_BLOCK * 64, 0, stream>>>(raw, zvals, rays_d, bg, out);
}